// Round 5
// baseline (174.361 us; speedup 1.0000x reference)
//
#include <hip/hip_runtime.h>
#include <stdint.h>

typedef unsigned short u16;
typedef __bf16 bf16_t;
typedef bf16_t v8bf __attribute__((ext_vector_type(8)));
typedef float v4f __attribute__((ext_vector_type(4)));

#define SEQ   4096
#define HIDN  1024
#define NHEAD 16
#define HDIM  64
#define BLK   256
#define NBLK  16

#define GLOAD_LDS16(g, l) __builtin_amdgcn_global_load_lds( \
  (const __attribute__((address_space(1))) unsigned*)(g), \
  (__attribute__((address_space(3))) unsigned*)(l), 16, 0, 0)

__device__ __forceinline__ u16 f2bf(float f){
  union { float f; unsigned u; } v; v.f = f;
  unsigned r = (v.u + 0x7fffu + ((v.u >> 16) & 1u)) >> 16;   // RNE
  return (u16)r;
}
__device__ __forceinline__ float bf2f(u16 h){
  union { unsigned u; float f; } v; v.u = ((unsigned)h) << 16;
  return v.f;
}

// ---------------- fused prep: W transposes + hidden convert + bcat + pos_proj ----------------
__global__ __launch_bounds__(256) void k_prep(const float* __restrict__ hidden, u16* __restrict__ hb,
    const float* __restrict__ Wq, const float* __restrict__ Wk,
    const float* __restrict__ Wv, const float* __restrict__ Wo, u16* __restrict__ Wt,
    const float* __restrict__ bq, const float* __restrict__ bk, const float* __restrict__ bv,
    float* __restrict__ bcat,
    const float* __restrict__ rpe, float* __restrict__ posk, float* __restrict__ posq0)
{
  __shared__ float t[32][33];
  __shared__ float red[4][64];
  int b = blockIdx.x, tid = threadIdx.x;
  if (b < 4096){
    int w = b >> 10, tile = b & 1023;
    int k0 = (tile & 31) * 32, n0 = (tile >> 5) * 32;
    const float* W = (w == 0) ? Wq : (w == 1) ? Wk : (w == 2) ? Wv : Wo;
    u16* outp = Wt + (size_t)w * 1024 * 1024;
    int x = tid & 31, y = tid >> 5;
    #pragma unroll
    for (int yy = 0; yy < 32; yy += 8) t[y + yy][x] = W[(size_t)(k0 + y + yy) * 1024 + n0 + x];
    __syncthreads();
    #pragma unroll
    for (int yy = 0; yy < 32; yy += 8) outp[(size_t)(n0 + y + yy) * 1024 + k0 + x] = f2bf(t[x][y + yy]);
  } else if (b < 4608){
    int base = (b - 4096) * 8192;
    #pragma unroll
    for (int j = 0; j < 8; j++){
      int i = base + j * 1024 + tid * 4;
      float4 f = *(const float4*)&hidden[i];
      unsigned u0 = (unsigned)f2bf(f.x) | ((unsigned)f2bf(f.y) << 16);
      unsigned u1 = (unsigned)f2bf(f.z) | ((unsigned)f2bf(f.w) << 16);
      uint2 p; p.x = u0; p.y = u1;
      *(uint2*)&hb[i] = p;
    }
  } else if (b == 4608){
    #pragma unroll
    for (int j = 0; j < 12; j++){
      int i = j * 256 + tid;
      const float* src = i < 1024 ? bq : (i < 2048 ? bk : bv);
      bcat[i] = src[i & 1023];
    }
  } else {
    int pb = b - 4609;   // [0,257)
    int d = tid & 63, part = tid >> 6;
    const float* W  = (pb < 256) ? Wk : Wq;
    const float* rv = (pb < 256) ? &rpe[(size_t)pb * 1024] : rpe;
    float s = 0.f;
    for (int k = part * 256; k < part * 256 + 256; k++) s += rv[k] * W[(size_t)k * 1024 + d];
    red[part][d] = s;
    __syncthreads();
    if (part == 0){
      s = red[0][d] + red[1][d] + red[2][d] + red[3][d];
      if (pb < 256) posk[pb * 64 + d] = s + bk[d];
      else          posq0[d] = s + bq[d];
    }
  }
}

// ---------------- QKV GEMM (m97 structure): qk[S][2048] = Q|K ; Vt[c][s] for V ----------------
__global__ __launch_bounds__(256) void k_gemm_qkv(const u16* __restrict__ A, const u16* __restrict__ Bt,
                                                  const float* __restrict__ bias,
                                                  u16* __restrict__ qk, u16* __restrict__ Vt)
{
  __shared__ alignas(16) u16 As[128 * 32];
  __shared__ alignas(16) u16 Bs[128 * 32];
  int tid = threadIdx.x, lane = tid & 63, wid = tid >> 6;
  int wr = wid >> 1, wc = wid & 1;
  int m0 = blockIdx.y * 128, n0 = blockIdx.x * 128;
  const int K = 1024;

  v4f acc[4][4];
  #pragma unroll
  for (int m = 0; m < 4; m++)
    #pragma unroll
    for (int n = 0; n < 4; n++) acc[m][n] = (v4f){0.f, 0.f, 0.f, 0.f};

  int r = lane & 15, g = lane >> 4;
  int ob0 = wid * 2048;

  for (int kt = 0; kt < K; kt += 32){
    #pragma unroll
    for (int t = 0; t < 2; ++t){
      int ob = ob0 + t * 1024;
      int o  = ob + lane * 16;
      int row = o >> 6, col = (o & 63) >> 1;
      GLOAD_LDS16(&A [(size_t)(m0 + row) * K + kt + col], As + (ob >> 1));
      GLOAD_LDS16(&Bt[(size_t)(n0 + row) * K + kt + col], Bs + (ob >> 1));
    }
    __syncthreads();
    v8bf a[4], bb[4];
    #pragma unroll
    for (int m = 0; m < 4; m++) a[m] = *(const v8bf*)&As[(wr * 64 + m * 16 + r) * 32 + g * 8];
    #pragma unroll
    for (int n = 0; n < 4; n++) bb[n] = *(const v8bf*)&Bs[(wc * 64 + n * 16 + r) * 32 + g * 8];
    #pragma unroll
    for (int m = 0; m < 4; m++)
      #pragma unroll
      for (int n = 0; n < 4; n++)
        acc[m][n] = __builtin_amdgcn_mfma_f32_16x16x32_bf16(a[m], bb[n], acc[m][n], 0, 0, 0);
    __syncthreads();
  }

  #pragma unroll
  for (int m = 0; m < 4; m++)
    #pragma unroll
    for (int n = 0; n < 4; n++){
      int col = n0 + wc * 64 + n * 16 + r;
      float bv = bias[col];
      #pragma unroll
      for (int i = 0; i < 4; i++){
        int row = m0 + wr * 64 + m * 16 + g * 4 + i;
        u16 h = f2bf(acc[m][n][i] + bv);
        if (col < 2048) qk[(size_t)row * 2048 + col] = h;
        else            Vt[(size_t)(col - 2048) * 4096 + row] = h;   // V stored transposed
      }
    }
}

// ---------------- out GEMM + residual ----------------
__global__ __launch_bounds__(256) void k_gemm_out(const u16* __restrict__ A, const u16* __restrict__ Bt,
                                                  const float* __restrict__ bias,
                                                  const float* __restrict__ resid, float* __restrict__ Cout)
{
  __shared__ alignas(16) u16 As[128 * 32];
  __shared__ alignas(16) u16 Bs[128 * 32];
  int tid = threadIdx.x, lane = tid & 63, wid = tid >> 6;
  int wr = wid >> 1, wc = wid & 1;
  int m0 = blockIdx.y * 128, n0 = blockIdx.x * 128;
  const int K = 1024;

  v4f acc[4][4];
  #pragma unroll
  for (int m = 0; m < 4; m++)
    #pragma unroll
    for (int n = 0; n < 4; n++) acc[m][n] = (v4f){0.f, 0.f, 0.f, 0.f};

  int r = lane & 15, g = lane >> 4;
  int ob0 = wid * 2048;

  for (int kt = 0; kt < K; kt += 32){
    #pragma unroll
    for (int t = 0; t < 2; ++t){
      int ob = ob0 + t * 1024;
      int o  = ob + lane * 16;
      int row = o >> 6, col = (o & 63) >> 1;
      GLOAD_LDS16(&A [(size_t)(m0 + row) * K + kt + col], As + (ob >> 1));
      GLOAD_LDS16(&Bt[(size_t)(n0 + row) * K + kt + col], Bs + (ob >> 1));
    }
    __syncthreads();
    v8bf a[4], bb[4];
    #pragma unroll
    for (int m = 0; m < 4; m++) a[m] = *(const v8bf*)&As[(wr * 64 + m * 16 + r) * 32 + g * 8];
    #pragma unroll
    for (int n = 0; n < 4; n++) bb[n] = *(const v8bf*)&Bs[(wc * 64 + n * 16 + r) * 32 + g * 8];
    #pragma unroll
    for (int m = 0; m < 4; m++)
      #pragma unroll
      for (int n = 0; n < 4; n++)
        acc[m][n] = __builtin_amdgcn_mfma_f32_16x16x32_bf16(a[m], bb[n], acc[m][n], 0, 0, 0);
    __syncthreads();
  }

  #pragma unroll
  for (int m = 0; m < 4; m++)
    #pragma unroll
    for (int n = 0; n < 4; n++){
      int col = n0 + wc * 64 + n * 16 + r;
      float bv = bias[col];
      #pragma unroll
      for (int i = 0; i < 4; i++){
        int row = m0 + wr * 64 + m * 16 + g * 4 + i;
        Cout[(size_t)row * 1024 + col] = acc[m][n][i] + bv + resid[(size_t)row * 1024 + col];
      }
    }
}

// ---------------- bias kernel (one block): brow[512] then biasd[1024] ----------------
__global__ __launch_bounds__(256) void k_bias(const u16* __restrict__ qk,
                                              const float* __restrict__ posk, const float* __restrict__ posq0,
                                              float* __restrict__ biasd)
{
  __shared__ float brow[512];
  int tid = threadIdx.x;
  brow[tid] = 0.f;
  {
    int u = tid;
    float c2p = 0.f, p2c = 0.f;
    for (int d = 0; d < 64; d++){
      c2p += bf2f(qk[d]) * posk[u * 64 + d];                  // q row0 head0
      p2c += posq0[d] * bf2f(qk[(size_t)u * 2048 + 1024 + d]); // k row u head0
    }
    brow[256 + u] = c2p + p2c;
  }
  __syncthreads();
  #pragma unroll
  for (int j = 0; j < 4; j++){
    int t = tid + j * 256;   // [0,1024)
    int rel = t - 767;
    int bucket;
    bool in_exact = (rel < 128) && (rel > -128);
    int abs_pos = in_exact ? 127 : (rel < 0 ? -rel : rel);
    if (abs_pos <= 128) bucket = rel;
    else {
      float xx = logf((float)abs_pos * (1.0f / 128.0f)) / logf(255.0f / 128.0f);
      float lp = ceilf(xx * 127.0f) + 128.0f;
      int sgn = (rel > 0) ? 1 : ((rel < 0) ? -1 : 0);
      bucket = (int)lp * sgn;
    }
    int idx = bucket + 256;
    idx = idx < 0 ? 0 : (idx > 511 ? 511 : idx);
    biasd[t] = brow[idx];
  }
}

// ---------------- fused local attention: WG = (n, h, qtile of 16 rows) ----------------
// All staging via global_load_lds with pre-swizzled sources (linear LDS, slot ^= row&7).
// Ss scores stored with col ^= (g<<4) swizzle keyed on row quad; reads undo it.
__global__ __launch_bounds__(256) void k_attn(const u16* __restrict__ qk, const u16* __restrict__ Vt,
                                              const float* __restrict__ biasd, u16* __restrict__ ctxg)
{
  __shared__ alignas(16) u16 Qs[16 * 64];      // 2KB  [q][64]   slot-swizzled
  __shared__ alignas(16) u16 KVs[8192];        // 16KB: K [128][64] or V [64][128], slot-swizzled
  __shared__ alignas(16) u16 Ss[16 * 776];     // 24.8KB scores/probs, col-swizzled
  __shared__ float bias_s[1024];
  __shared__ float wmax[64];
  __shared__ float invsum[16];

  int b = blockIdx.x;
  int qt = b & 15, h = (b >> 4) & 15, n = b >> 8;
  int tid = threadIdx.x, lane = tid & 63, w = tid >> 6;
  int q0 = n * 256 + qt * 16;
  int qb0 = qt * 16;
  int g0 = (n - 1) * 256;
  const float inv_scale = 0.07216878364870323f;  // 1/sqrt(192)

  int r = lane & 15, g = lane >> 4;

  // stage Q [16][64] (waves 0,1) ; bias table (all threads)
  if (w < 2){
    int o = w * 1024 + lane * 16;
    int row = o >> 7, p = (o >> 4) & 7;
    GLOAD_LDS16(&qk[(size_t)(q0 + row) * 2048 + h * 64 + ((p ^ (row & 7)) * 8)],
                ((u16*)Qs) + w * 512);
  }
  *(float4*)&bias_s[tid * 4] = *(const float4*)&biasd[tid * 4];

  // ---- phase 1: scores -> Ss, track row max in regs ----
  float m4[4];
  #pragma unroll
  for (int i = 0; i < 4; i++) m4[i] = -3.0e38f;

  for (int c = 0; c < 6; ++c){
    int cb = g0 + c * 128;
    bool oob = (cb < 0) || (cb >= SEQ);
    if (!oob){
      #pragma unroll
      for (int t = 0; t < 4; ++t){   // K chunk [128][64], 4 gll per wave
        int o = (w * 4 + t) * 1024 + lane * 16;
        int row = o >> 7, p = (o >> 4) & 7;
        GLOAD_LDS16(&qk[(size_t)(cb + row) * 2048 + 1024 + h * 64 + ((p ^ (row & 7)) * 8)],
                    ((u16*)KVs) + (w * 4 + t) * 512);
      }
    }
    __syncthreads();
    v4f sacc[2];
    sacc[0] = (v4f){0.f,0.f,0.f,0.f};
    sacc[1] = (v4f){0.f,0.f,0.f,0.f};
    if (!oob){
      #pragma unroll
      for (int ks = 0; ks < 2; ++ks){
        v8bf a = *(const v8bf*)&Qs[r * 64 + ((4 * ks + g) ^ (r & 7)) * 8];
        #pragma unroll
        for (int nn = 0; nn < 2; nn++){
          int kr = w * 32 + nn * 16 + r;
          v8bf bb = *(const v8bf*)&KVs[kr * 64 + ((4 * ks + g) ^ (kr & 7)) * 8];
          sacc[nn] = __builtin_amdgcn_mfma_f32_16x16x32_bf16(a, bb, sacc[nn], 0, 0, 0);
        }
      }
    }
    #pragma unroll
    for (int nn = 0; nn < 2; nn++){
      int kcol = c * 128 + w * 32 + nn * 16 + r;
      int scol = kcol ^ (g << 4);
      #pragma unroll
      for (int i = 0; i < 4; i++){
        int qrow = g * 4 + i;
        float sc = (sacc[nn][i] + bias_s[qb0 + qrow - kcol + 767]) * inv_scale;
        m4[i] = fmaxf(m4[i], sc);
        Ss[qrow * 776 + scol] = f2bf(sc);
      }
    }
    __syncthreads();
  }

  // cross-lane (r) then cross-wave max combine
  #pragma unroll
  for (int i = 0; i < 4; i++){
    m4[i] = fmaxf(m4[i], __shfl_xor(m4[i], 1));
    m4[i] = fmaxf(m4[i], __shfl_xor(m4[i], 2));
    m4[i] = fmaxf(m4[i], __shfl_xor(m4[i], 4));
    m4[i] = fmaxf(m4[i], __shfl_xor(m4[i], 8));
  }
  if (r == 0){
    #pragma unroll
    for (int i = 0; i < 4; i++) wmax[w * 16 + g * 4 + i] = m4[i];
  }
  __syncthreads();

  // ---- phase 2: exp + sum (16 threads/row), store unnormalized probs ----
  {
    int row = tid >> 4, sub = tid & 15;
    float mx = fmaxf(fmaxf(wmax[row], wmax[16 + row]), fmaxf(wmax[32 + row], wmax[48 + row]));
    u16* srow = &Ss[row * 776 + sub * 48];
    float sm = 0.f;
    #pragma unroll
    for (int ii = 0; ii < 6; ii++){
      uint4 pk = *(const uint4*)&srow[ii * 8];
      unsigned* wd = (unsigned*)&pk;
      #pragma unroll
      for (int j = 0; j < 4; j++){
        float e0 = __expf(bf2f((u16)(wd[j] & 0xffff)) - mx);
        float e1 = __expf(bf2f((u16)(wd[j] >> 16)) - mx);
        sm += e0 + e1;
        wd[j] = (unsigned)f2bf(e0) | ((unsigned)f2bf(e1) << 16);
      }
      *(uint4*)&srow[ii * 8] = pk;
    }
    sm += __shfl_xor(sm, 1);
    sm += __shfl_xor(sm, 2);
    sm += __shfl_xor(sm, 4);
    sm += __shfl_xor(sm, 8);
    if (sub == 0) invsum[row] = 1.0f / sm;
  }
  __syncthreads();

  // ---- phase 3: PV ----
  v4f pacc = (v4f){0.f,0.f,0.f,0.f};
  int key = (r >> 2) & 3;
  for (int c = 0; c < 6; ++c){
    int cb = g0 + c * 128;
    bool oob = (cb < 0) || (cb >= SEQ);
    if (!oob){
      #pragma unroll
      for (int t = 0; t < 4; ++t){   // V chunk [64][128], 4 gll per wave
        int o = (w * 4 + t) * 1024 + lane * 16;
        int d = o >> 8, p = (o >> 4) & 15;
        GLOAD_LDS16(&Vt[(size_t)(h * 64 + d) * 4096 + cb + ((p ^ (d & 7)) * 8)],
                    ((u16*)KVs) + (w * 4 + t) * 512);
      }
    }
    __syncthreads();
    if (!oob){
      int d = w * 16 + r;
      #pragma unroll
      for (int ks = 0; ks < 4; ++ks){
        int col = (c * 128 + ks * 32 + g * 8) ^ (key << 4);
        v8bf a  = *(const v8bf*)&Ss[r * 776 + col];
        v8bf bb = *(const v8bf*)&KVs[d * 128 + ((4 * ks + g) ^ (r & 7)) * 8];
        pacc = __builtin_amdgcn_mfma_f32_16x16x32_bf16(a, bb, pacc, 0, 0, 0);
      }
    }
    __syncthreads();
  }
  {
    int d = w * 16 + r;
    #pragma unroll
    for (int i = 0; i < 4; i++){
      int qrow = g * 4 + i;
      ctxg[(size_t)(q0 + qrow) * 1024 + h * 64 + d] = f2bf(pacc[i] * invsum[qrow]);
    }
  }
}

// ---------------- LayerNorm in place (residual already folded into out) ----------------
__global__ __launch_bounds__(256) void k_ln(float* __restrict__ out,
                                            const float* __restrict__ gamma, const float* __restrict__ beta)
{
  __shared__ float red[8];
  int row = blockIdx.x, tid = threadIdx.x;
  int lane = tid & 63, wid = tid >> 6;
  size_t base = (size_t)row * 1024 + tid * 4;
  float4 xv = *(const float4*)&out[base];
  float v0 = xv.x, v1 = xv.y, v2 = xv.z, v3 = xv.w;
  float s = v0 + v1 + v2 + v3;
  float q = v0 * v0 + v1 * v1 + v2 * v2 + v3 * v3;
  #pragma unroll
  for (int o = 32; o; o >>= 1){ s += __shfl_down(s, o); q += __shfl_down(q, o); }
  if (lane == 0){ red[wid] = s; red[4 + wid] = q; }
  __syncthreads();
  float ts = red[0] + red[1] + red[2] + red[3];
  float tq = red[4] + red[5] + red[6] + red[7];
  float mu = ts * (1.0f / 1024.0f);
  float var = tq * (1.0f / 1024.0f) - mu * mu;
  float rstd = rsqrtf(var + 1e-7f);
  int c = tid * 4;
  out[base + 0] = (v0 - mu) * rstd * gamma[c + 0] + beta[c + 0];
  out[base + 1] = (v1 - mu) * rstd * gamma[c + 1] + beta[c + 1];
  out[base + 2] = (v2 - mu) * rstd * gamma[c + 2] + beta[c + 2];
  out[base + 3] = (v3 - mu) * rstd * gamma[c + 3] + beta[c + 3];
}

extern "C" void kernel_launch(void* const* d_in, const int* in_sizes, int n_in,
                              void* d_out, int out_size, void* d_ws, size_t ws_size,
                              hipStream_t stream)
{
  const float* hidden = (const float*)d_in[0];
  const float* rpe    = (const float*)d_in[1];
  const float* Wq = (const float*)d_in[2];
  const float* bq = (const float*)d_in[3];
  const float* Wk = (const float*)d_in[4];
  const float* bk = (const float*)d_in[5];
  const float* Wv = (const float*)d_in[6];
  const float* bv = (const float*)d_in[7];
  const float* Wo = (const float*)d_in[8];
  const float* bo = (const float*)d_in[9];
  const float* lns = (const float*)d_in[10];
  const float* lnb = (const float*)d_in[11];
  float* out = (float*)d_out;

  char* ws = (char*)d_ws;
  size_t off = 0;
  auto alloc = [&](size_t bytes){ void* p = ws + off; off += (bytes + 255) & ~(size_t)255; return p; };
  u16* hb      = (u16*)alloc((size_t)SEQ * HIDN * 2);
  u16* Wt      = (u16*)alloc((size_t)4 * HIDN * HIDN * 2);    // [Wqt|Wkt|Wvt|Wot]
  u16* qk      = (u16*)alloc((size_t)SEQ * 2048 * 2);
  u16* Vt      = (u16*)alloc((size_t)HIDN * SEQ * 2);
  u16* ctxb    = (u16*)alloc((size_t)SEQ * HIDN * 2);
  float* bcat  = (float*)alloc(3072 * 4);
  float* poskf = (float*)alloc(256 * 64 * 4);
  float* posq0 = (float*)alloc(64 * 4);
  float* biasd = (float*)alloc(1024 * 4);
  (void)ws_size; (void)in_sizes; (void)n_in; (void)out_size;

  k_prep<<<4866, 256, 0, stream>>>(hidden, hb, Wq, Wk, Wv, Wo, Wt,
                                   bq, bk, bv, bcat, rpe, poskf, posq0);

  k_gemm_qkv<<<dim3(24, 32), 256, 0, stream>>>(hb, Wt, bcat, qk, Vt);

  k_bias<<<1, 256, 0, stream>>>(qk, poskf, posq0, biasd);

  k_attn<<<NBLK * NHEAD * 16, 256, 0, stream>>>(qk, Vt, biasd, ctxb);

  k_gemm_out<<<dim3(8, 32), 256, 0, stream>>>(ctxb, Wt + (size_t)3 * HIDN * HIDN, bo, hidden, out);

  k_ln<<<SEQ, 256, 0, stream>>>(out, lns, lnb);
}

// Round 6
// 172.610 us; speedup vs baseline: 1.0101x; 1.0101x over previous
//
#include <hip/hip_runtime.h>
#include <stdint.h>

typedef unsigned short u16;
typedef __bf16 bf16_t;
typedef bf16_t v8bf __attribute__((ext_vector_type(8)));
typedef float v4f __attribute__((ext_vector_type(4)));

#define SEQ   4096
#define HIDN  1024
#define NHEAD 16
#define HDIM  64
#define BLK   256
#define NBLK  16

#define GLOAD_LDS16(g, l) __builtin_amdgcn_global_load_lds( \
  (const __attribute__((address_space(1))) unsigned*)(g), \
  (__attribute__((address_space(3))) unsigned*)(l), 16, 0, 0)

__device__ __forceinline__ u16 f2bf(float f){
  union { float f; unsigned u; } v; v.f = f;
  unsigned r = (v.u + 0x7fffu + ((v.u >> 16) & 1u)) >> 16;   // RNE
  return (u16)r;
}
__device__ __forceinline__ float bf2f(u16 h){
  union { unsigned u; float f; } v; v.u = ((unsigned)h) << 16;
  return v.f;
}

// ---------------- fused prep: W transposes + hidden convert + bcat + pos_proj ----------------
__global__ __launch_bounds__(256) void k_prep(const float* __restrict__ hidden, u16* __restrict__ hb,
    const float* __restrict__ Wq, const float* __restrict__ Wk,
    const float* __restrict__ Wv, const float* __restrict__ Wo, u16* __restrict__ Wt,
    const float* __restrict__ bq, const float* __restrict__ bk, const float* __restrict__ bv,
    float* __restrict__ bcat,
    const float* __restrict__ rpe, float* __restrict__ posk, float* __restrict__ posq0)
{
  __shared__ float t[32][33];
  __shared__ float red[4][64];
  int b = blockIdx.x, tid = threadIdx.x;
  if (b < 4096){
    int w = b >> 10, tile = b & 1023;
    int k0 = (tile & 31) * 32, n0 = (tile >> 5) * 32;
    const float* W = (w == 0) ? Wq : (w == 1) ? Wk : (w == 2) ? Wv : Wo;
    u16* outp = Wt + (size_t)w * 1024 * 1024;
    int x = tid & 31, y = tid >> 5;
    #pragma unroll
    for (int yy = 0; yy < 32; yy += 8) t[y + yy][x] = W[(size_t)(k0 + y + yy) * 1024 + n0 + x];
    __syncthreads();
    #pragma unroll
    for (int yy = 0; yy < 32; yy += 8) outp[(size_t)(n0 + y + yy) * 1024 + k0 + x] = f2bf(t[x][y + yy]);
  } else if (b < 4608){
    int base = (b - 4096) * 8192;
    #pragma unroll
    for (int j = 0; j < 8; j++){
      int i = base + j * 1024 + tid * 4;
      float4 f = *(const float4*)&hidden[i];
      unsigned u0 = (unsigned)f2bf(f.x) | ((unsigned)f2bf(f.y) << 16);
      unsigned u1 = (unsigned)f2bf(f.z) | ((unsigned)f2bf(f.w) << 16);
      uint2 p; p.x = u0; p.y = u1;
      *(uint2*)&hb[i] = p;
    }
  } else if (b == 4608){
    #pragma unroll
    for (int j = 0; j < 12; j++){
      int i = j * 256 + tid;
      const float* src = i < 1024 ? bq : (i < 2048 ? bk : bv);
      bcat[i] = src[i & 1023];
    }
  } else {
    int pb = b - 4609;   // [0,257)
    int d = tid & 63, part = tid >> 6;
    const float* W  = (pb < 256) ? Wk : Wq;
    const float* rv = (pb < 256) ? &rpe[(size_t)pb * 1024] : rpe;
    float s = 0.f;
    for (int k = part * 256; k < part * 256 + 256; k++) s += rv[k] * W[(size_t)k * 1024 + d];
    red[part][d] = s;
    __syncthreads();
    if (part == 0){
      s = red[0][d] + red[1][d] + red[2][d] + red[3][d];
      if (pb < 256) posk[pb * 64 + d] = s + bk[d];
      else          posq0[d] = s + bq[d];
    }
  }
}

// ---------------- QKV GEMM (m97 structure): qk[S][2048] = Q|K ; Vt[c][s] for V ----------------
__global__ __launch_bounds__(256) void k_gemm_qkv(const u16* __restrict__ A, const u16* __restrict__ Bt,
                                                  const float* __restrict__ bias,
                                                  u16* __restrict__ qk, u16* __restrict__ Vt)
{
  __shared__ alignas(16) u16 As[128 * 32];
  __shared__ alignas(16) u16 Bs[128 * 32];
  int tid = threadIdx.x, lane = tid & 63, wid = tid >> 6;
  int wr = wid >> 1, wc = wid & 1;
  int m0 = blockIdx.y * 128, n0 = blockIdx.x * 128;
  const int K = 1024;

  v4f acc[4][4];
  #pragma unroll
  for (int m = 0; m < 4; m++)
    #pragma unroll
    for (int n = 0; n < 4; n++) acc[m][n] = (v4f){0.f, 0.f, 0.f, 0.f};

  int r = lane & 15, g = lane >> 4;
  int ob0 = wid * 2048;

  for (int kt = 0; kt < K; kt += 32){
    #pragma unroll
    for (int t = 0; t < 2; ++t){
      int ob = ob0 + t * 1024;
      int o  = ob + lane * 16;
      int row = o >> 6, col = (o & 63) >> 1;
      GLOAD_LDS16(&A [(size_t)(m0 + row) * K + kt + col], As + (ob >> 1));
      GLOAD_LDS16(&Bt[(size_t)(n0 + row) * K + kt + col], Bs + (ob >> 1));
    }
    __syncthreads();
    v8bf a[4], bb[4];
    #pragma unroll
    for (int m = 0; m < 4; m++) a[m] = *(const v8bf*)&As[(wr * 64 + m * 16 + r) * 32 + g * 8];
    #pragma unroll
    for (int n = 0; n < 4; n++) bb[n] = *(const v8bf*)&Bs[(wc * 64 + n * 16 + r) * 32 + g * 8];
    #pragma unroll
    for (int m = 0; m < 4; m++)
      #pragma unroll
      for (int n = 0; n < 4; n++)
        acc[m][n] = __builtin_amdgcn_mfma_f32_16x16x32_bf16(a[m], bb[n], acc[m][n], 0, 0, 0);
    __syncthreads();
  }

  #pragma unroll
  for (int m = 0; m < 4; m++)
    #pragma unroll
    for (int n = 0; n < 4; n++){
      int col = n0 + wc * 64 + n * 16 + r;
      float bv = bias[col];
      #pragma unroll
      for (int i = 0; i < 4; i++){
        int row = m0 + wr * 64 + m * 16 + g * 4 + i;
        u16 h = f2bf(acc[m][n][i] + bv);
        if (col < 2048) qk[(size_t)row * 2048 + col] = h;
        else            Vt[(size_t)(col - 2048) * 4096 + row] = h;   // V stored transposed
      }
    }
}

// ---------------- out GEMM + residual ----------------
__global__ __launch_bounds__(256) void k_gemm_out(const u16* __restrict__ A, const u16* __restrict__ Bt,
                                                  const float* __restrict__ bias,
                                                  const float* __restrict__ resid, float* __restrict__ Cout)
{
  __shared__ alignas(16) u16 As[128 * 32];
  __shared__ alignas(16) u16 Bs[128 * 32];
  int tid = threadIdx.x, lane = tid & 63, wid = tid >> 6;
  int wr = wid >> 1, wc = wid & 1;
  int m0 = blockIdx.y * 128, n0 = blockIdx.x * 128;
  const int K = 1024;

  v4f acc[4][4];
  #pragma unroll
  for (int m = 0; m < 4; m++)
    #pragma unroll
    for (int n = 0; n < 4; n++) acc[m][n] = (v4f){0.f, 0.f, 0.f, 0.f};

  int r = lane & 15, g = lane >> 4;
  int ob0 = wid * 2048;

  for (int kt = 0; kt < K; kt += 32){
    #pragma unroll
    for (int t = 0; t < 2; ++t){
      int ob = ob0 + t * 1024;
      int o  = ob + lane * 16;
      int row = o >> 6, col = (o & 63) >> 1;
      GLOAD_LDS16(&A [(size_t)(m0 + row) * K + kt + col], As + (ob >> 1));
      GLOAD_LDS16(&Bt[(size_t)(n0 + row) * K + kt + col], Bs + (ob >> 1));
    }
    __syncthreads();
    v8bf a[4], bb[4];
    #pragma unroll
    for (int m = 0; m < 4; m++) a[m] = *(const v8bf*)&As[(wr * 64 + m * 16 + r) * 32 + g * 8];
    #pragma unroll
    for (int n = 0; n < 4; n++) bb[n] = *(const v8bf*)&Bs[(wc * 64 + n * 16 + r) * 32 + g * 8];
    #pragma unroll
    for (int m = 0; m < 4; m++)
      #pragma unroll
      for (int n = 0; n < 4; n++)
        acc[m][n] = __builtin_amdgcn_mfma_f32_16x16x32_bf16(a[m], bb[n], acc[m][n], 0, 0, 0);
    __syncthreads();
  }

  #pragma unroll
  for (int m = 0; m < 4; m++)
    #pragma unroll
    for (int n = 0; n < 4; n++){
      int col = n0 + wc * 64 + n * 16 + r;
      float bv = bias[col];
      #pragma unroll
      for (int i = 0; i < 4; i++){
        int row = m0 + wr * 64 + m * 16 + g * 4 + i;
        Cout[(size_t)row * 1024 + col] = acc[m][n][i] + bv + resid[(size_t)row * 1024 + col];
      }
    }
}

// ---------------- brow: 8 WGs, 32 rows each; also zeros brow[0,256) ----------------
__global__ __launch_bounds__(256) void k_brow(const u16* __restrict__ qk,
                                              const float* __restrict__ posk, const float* __restrict__ posq0,
                                              float* __restrict__ brow)
{
  int b = blockIdx.x, tid = threadIdx.x;
  if (tid < 32) brow[b * 32 + tid] = 0.f;        // zero [0,256) across the 8 blocks
  int u = b * 32 + (tid >> 3), sub = tid & 7;
  float c2p = 0.f, p2c = 0.f;
  #pragma unroll
  for (int j = 0; j < 8; j++){
    int d = sub * 8 + j;
    c2p += bf2f(qk[d]) * posk[u * 64 + d];                   // q row0 head0
    p2c += posq0[d] * bf2f(qk[(size_t)u * 2048 + 1024 + d]); // k row u head0
  }
  float v = c2p + p2c;
  v += __shfl_xor(v, 1);
  v += __shfl_xor(v, 2);
  v += __shfl_xor(v, 4);
  if (sub == 0) brow[256 + u] = v;
}

// ---------------- biasd[t] = brow[clip(bucket(t-767)+256)] ----------------
__global__ void k_biasd(const float* __restrict__ brow, float* __restrict__ biasd)
{
  int t = blockIdx.x * blockDim.x + threadIdx.x;   // 1024
  int rel = t - 767;
  int bucket;
  bool in_exact = (rel < 128) && (rel > -128);
  int abs_pos = in_exact ? 127 : (rel < 0 ? -rel : rel);
  if (abs_pos <= 128) bucket = rel;
  else {
    float xx = logf((float)abs_pos * (1.0f / 128.0f)) / logf(255.0f / 128.0f);
    float lp = ceilf(xx * 127.0f) + 128.0f;
    int sgn = (rel > 0) ? 1 : ((rel < 0) ? -1 : 0);
    bucket = (int)lp * sgn;
  }
  int idx = bucket + 256;
  idx = idx < 0 ? 0 : (idx > 511 ? 511 : idx);
  biasd[t] = brow[idx];
}

// ---------------- fused local attention: register-resident scores ----------------
// WG = (n, h, qtile of 16 rows). Scores live in sc[6][2] (48 f32/thread) from QK
// through max/exp; LDS sees only the final bf16 probs (one scattered u16 store each).
__global__ __launch_bounds__(256) void k_attn(const u16* __restrict__ qk, const u16* __restrict__ Vt,
                                              const float* __restrict__ biasd, u16* __restrict__ ctxg)
{
  __shared__ alignas(16) u16 Qs[16 * 64];      // 2KB, slot-swizzled
  __shared__ alignas(16) u16 KVs[8192];        // 16KB: K [128][64] or V [64][128], slot-swizzled
  __shared__ alignas(16) u16 Ss[16 * 776];     // 24.8KB probs, col-swizzled
  __shared__ float bias_s[1024];
  __shared__ float wred[64];                   // per-wave row max, then row sum

  int b = blockIdx.x;
  int qt = b & 15, h = (b >> 4) & 15, n = b >> 8;
  int tid = threadIdx.x, lane = tid & 63, w = tid >> 6;
  int q0 = n * 256 + qt * 16;
  int qb0 = qt * 16;
  int g0 = (n - 1) * 256;
  // (1/sqrt(192)) * log2(e): prob = exp2(sc - max_sc)
  const float c1 = 0.07216878364870323f * 1.4426950408889634f;

  int r = lane & 15, g = lane >> 4;

  // stage Q [16][64] (waves 0,1) ; bias table (all threads)
  if (w < 2){
    int o = w * 1024 + lane * 16;
    int row = o >> 7, p = (o >> 4) & 7;
    GLOAD_LDS16(&qk[(size_t)(q0 + row) * 2048 + h * 64 + ((p ^ (row & 7)) * 8)],
                ((u16*)Qs) + w * 512);
  }
  *(float4*)&bias_s[tid * 4] = *(const float4*)&biasd[tid * 4];

  // ---- phase 1: QK -> sc regs, track row max ----
  float m4[4];
  #pragma unroll
  for (int i = 0; i < 4; i++) m4[i] = -3.0e38f;
  v4f sc[6][2];

  #pragma unroll
  for (int c = 0; c < 6; ++c){
    int cb = g0 + c * 128;
    bool oob = (cb < 0) || (cb >= SEQ);
    if (!oob){
      #pragma unroll
      for (int t = 0; t < 4; ++t){   // K chunk [128][64]
        int o = (w * 4 + t) * 1024 + lane * 16;
        int row = o >> 7, p = (o >> 4) & 7;
        GLOAD_LDS16(&qk[(size_t)(cb + row) * 2048 + 1024 + h * 64 + ((p ^ (row & 7)) * 8)],
                    ((u16*)KVs) + (w * 4 + t) * 512);
      }
    }
    __syncthreads();
    v4f sacc[2];
    sacc[0] = (v4f){0.f,0.f,0.f,0.f};
    sacc[1] = (v4f){0.f,0.f,0.f,0.f};
    if (!oob){
      #pragma unroll
      for (int ks = 0; ks < 2; ++ks){
        v8bf a = *(const v8bf*)&Qs[r * 64 + ((4 * ks + g) ^ (r & 7)) * 8];
        #pragma unroll
        for (int nn = 0; nn < 2; nn++){
          int kr = w * 32 + nn * 16 + r;
          v8bf bb = *(const v8bf*)&KVs[kr * 64 + ((4 * ks + g) ^ (kr & 7)) * 8];
          sacc[nn] = __builtin_amdgcn_mfma_f32_16x16x32_bf16(a, bb, sacc[nn], 0, 0, 0);
        }
      }
    }
    #pragma unroll
    for (int nn = 0; nn < 2; nn++){
      int kcol = c * 128 + w * 32 + nn * 16 + r;
      #pragma unroll
      for (int i = 0; i < 4; i++){
        float s = (sacc[nn][i] + bias_s[qb0 + g * 4 + i - kcol + 767]) * c1;
        m4[i] = fmaxf(m4[i], s);
        sc[c][nn] [i] = s;
      }
    }
    __syncthreads();
  }

  // row max: reduce over r lanes, then across waves via LDS
  #pragma unroll
  for (int i = 0; i < 4; i++){
    m4[i] = fmaxf(m4[i], __shfl_xor(m4[i], 1));
    m4[i] = fmaxf(m4[i], __shfl_xor(m4[i], 2));
    m4[i] = fmaxf(m4[i], __shfl_xor(m4[i], 4));
    m4[i] = fmaxf(m4[i], __shfl_xor(m4[i], 8));
  }
  if (r == 0){
    #pragma unroll
    for (int i = 0; i < 4; i++) wred[w * 16 + g * 4 + i] = m4[i];
  }
  __syncthreads();
  float mrow[4];
  #pragma unroll
  for (int i = 0; i < 4; i++){
    int row = g * 4 + i;
    mrow[i] = fmaxf(fmaxf(wred[row], wred[16 + row]), fmaxf(wred[32 + row], wred[48 + row]));
  }

  // ---- phase 2 (in regs): exp2, row sums, single bf16 store of probs ----
  float s4[4] = {0.f, 0.f, 0.f, 0.f};
  #pragma unroll
  for (int c = 0; c < 6; ++c){
    #pragma unroll
    for (int nn = 0; nn < 2; nn++){
      int kcol = c * 128 + w * 32 + nn * 16 + r;
      int scol = kcol ^ (g << 4);
      #pragma unroll
      for (int i = 0; i < 4; i++){
        float p = exp2f(sc[c][nn][i] - mrow[i]);
        s4[i] += p;
        Ss[(g * 4 + i) * 776 + scol] = f2bf(p);
      }
    }
  }
  #pragma unroll
  for (int i = 0; i < 4; i++){
    s4[i] += __shfl_xor(s4[i], 1);
    s4[i] += __shfl_xor(s4[i], 2);
    s4[i] += __shfl_xor(s4[i], 4);
    s4[i] += __shfl_xor(s4[i], 8);
  }
  __syncthreads();                       // mrow reads done -> wred reusable
  if (r == 0){
    #pragma unroll
    for (int i = 0; i < 4; i++) wred[w * 16 + g * 4 + i] = s4[i];
  }
  __syncthreads();                       // sums + Ss probs visible
  float inv4[4];
  #pragma unroll
  for (int i = 0; i < 4; i++){
    int row = g * 4 + i;
    inv4[i] = 1.0f / (wred[row] + wred[16 + row] + wred[32 + row] + wred[48 + row]);
  }

  // ---- phase 3: PV ----
  v4f pacc = (v4f){0.f,0.f,0.f,0.f};
  int key = (r >> 2) & 3;
  for (int c = 0; c < 6; ++c){
    int cb = g0 + c * 128;
    bool oob = (cb < 0) || (cb >= SEQ);
    if (!oob){
      #pragma unroll
      for (int t = 0; t < 4; ++t){   // V chunk [64][128]
        int o = (w * 4 + t) * 1024 + lane * 16;
        int d = o >> 8, p = (o >> 4) & 15;
        GLOAD_LDS16(&Vt[(size_t)(h * 64 + d) * 4096 + cb + ((p ^ (d & 7)) * 8)],
                    ((u16*)KVs) + (w * 4 + t) * 512);
      }
    }
    __syncthreads();
    if (!oob){
      int d = w * 16 + r;
      #pragma unroll
      for (int ks = 0; ks < 4; ++ks){
        int col = (c * 128 + ks * 32 + g * 8) ^ (key << 4);
        v8bf a  = *(const v8bf*)&Ss[r * 776 + col];
        v8bf bb = *(const v8bf*)&KVs[d * 128 + ((4 * ks + g) ^ (r & 7)) * 8];
        pacc = __builtin_amdgcn_mfma_f32_16x16x32_bf16(a, bb, pacc, 0, 0, 0);
      }
    }
    __syncthreads();
  }
  {
    int d = w * 16 + r;
    #pragma unroll
    for (int i = 0; i < 4; i++){
      int qrow = g * 4 + i;
      ctxg[(size_t)(q0 + qrow) * 1024 + h * 64 + d] = f2bf(pacc[i] * inv4[i]);
    }
  }
}

// ---------------- LayerNorm in place (residual already folded into out) ----------------
__global__ __launch_bounds__(256) void k_ln(float* __restrict__ out,
                                            const float* __restrict__ gamma, const float* __restrict__ beta)
{
  __shared__ float red[8];
  int row = blockIdx.x, tid = threadIdx.x;
  int lane = tid & 63, wid = tid >> 6;
  size_t base = (size_t)row * 1024 + tid * 4;
  float4 xv = *(const float4*)&out[base];
  float v0 = xv.x, v1 = xv.y, v2 = xv.z, v3 = xv.w;
  float s = v0 + v1 + v2 + v3;
  float q = v0 * v0 + v1 * v1 + v2 * v2 + v3 * v3;
  #pragma unroll
  for (int o = 32; o; o >>= 1){ s += __shfl_down(s, o); q += __shfl_down(q, o); }
  if (lane == 0){ red[wid] = s; red[4 + wid] = q; }
  __syncthreads();
  float ts = red[0] + red[1] + red[2] + red[3];
  float tq = red[4] + red[5] + red[6] + red[7];
  float mu = ts * (1.0f / 1024.0f);
  float var = tq * (1.0f / 1024.0f) - mu * mu;
  float rstd = rsqrtf(var + 1e-7f);
  int c = tid * 4;
  out[base + 0] = (v0 - mu) * rstd * gamma[c + 0] + beta[c + 0];
  out[base + 1] = (v1 - mu) * rstd * gamma[c + 1] + beta[c + 1];
  out[base + 2] = (v2 - mu) * rstd * gamma[c + 2] + beta[c + 2];
  out[base + 3] = (v3 - mu) * rstd * gamma[c + 3] + beta[c + 3];
}

extern "C" void kernel_launch(void* const* d_in, const int* in_sizes, int n_in,
                              void* d_out, int out_size, void* d_ws, size_t ws_size,
                              hipStream_t stream)
{
  const float* hidden = (const float*)d_in[0];
  const float* rpe    = (const float*)d_in[1];
  const float* Wq = (const float*)d_in[2];
  const float* bq = (const float*)d_in[3];
  const float* Wk = (const float*)d_in[4];
  const float* bk = (const float*)d_in[5];
  const float* Wv = (const float*)d_in[6];
  const float* bv = (const float*)d_in[7];
  const float* Wo = (const float*)d_in[8];
  const float* bo = (const float*)d_in[9];
  const float* lns = (const float*)d_in[10];
  const float* lnb = (const float*)d_in[11];
  float* out = (float*)d_out;

  char* ws = (char*)d_ws;
  size_t off = 0;
  auto alloc = [&](size_t bytes){ void* p = ws + off; off += (bytes + 255) & ~(size_t)255; return p; };
  u16* hb      = (u16*)alloc((size_t)SEQ * HIDN * 2);
  u16* Wt      = (u16*)alloc((size_t)4 * HIDN * HIDN * 2);    // [Wqt|Wkt|Wvt|Wot]
  u16* qk      = (u16*)alloc((size_t)SEQ * 2048 * 2);
  u16* Vt      = (u16*)alloc((size_t)HIDN * SEQ * 2);
  u16* ctxb    = (u16*)alloc((size_t)SEQ * HIDN * 2);
  float* bcat  = (float*)alloc(3072 * 4);
  float* poskf = (float*)alloc(256 * 64 * 4);
  float* posq0 = (float*)alloc(64 * 4);
  float* brow  = (float*)alloc(512 * 4);
  float* biasd = (float*)alloc(1024 * 4);
  (void)ws_size; (void)in_sizes; (void)n_in; (void)out_size;

  k_prep<<<4866, 256, 0, stream>>>(hidden, hb, Wq, Wk, Wv, Wo, Wt,
                                   bq, bk, bv, bcat, rpe, poskf, posq0);

  k_gemm_qkv<<<dim3(24, 32), 256, 0, stream>>>(hb, Wt, bcat, qk, Vt);

  k_brow<<<8, 256, 0, stream>>>(qk, poskf, posq0, brow);
  k_biasd<<<4, 256, 0, stream>>>(brow, biasd);

  k_attn<<<NBLK * NHEAD * 16, 256, 0, stream>>>(qk, Vt, biasd, ctxb);

  k_gemm_out<<<dim3(8, 32), 256, 0, stream>>>(ctxb, Wt + (size_t)3 * HIDN * HIDN, bo, hidden, out);

  k_ln<<<SEQ, 256, 0, stream>>>(out, lns, lnb);
}

// Round 7
// 151.767 us; speedup vs baseline: 1.1489x; 1.1373x over previous
//
#include <hip/hip_runtime.h>
#include <stdint.h>

typedef unsigned short u16;
typedef __bf16 bf16_t;
typedef bf16_t v8bf __attribute__((ext_vector_type(8)));
typedef float v4f __attribute__((ext_vector_type(4)));

#define SEQ   4096
#define HIDN  1024
#define NHEAD 16
#define HDIM  64
#define BLK   256
#define NBLK  16

#define GLOAD_LDS16(g, l) __builtin_amdgcn_global_load_lds( \
  (const __attribute__((address_space(1))) unsigned*)(g), \
  (__attribute__((address_space(3))) unsigned*)(l), 16, 0, 0)

__device__ __forceinline__ u16 f2bf(float f){
  union { float f; unsigned u; } v; v.f = f;
  unsigned r = (v.u + 0x7fffu + ((v.u >> 16) & 1u)) >> 16;   // RNE
  return (u16)r;
}
__device__ __forceinline__ float bf2f(u16 h){
  union { unsigned u; float f; } v; v.u = ((unsigned)h) << 16;
  return v.f;
}

// ---------------- fused prep: W transposes + hidden convert + bcat + pos_proj ----------------
__global__ __launch_bounds__(256) void k_prep(const float* __restrict__ hidden, u16* __restrict__ hb,
    const float* __restrict__ Wq, const float* __restrict__ Wk,
    const float* __restrict__ Wv, const float* __restrict__ Wo, u16* __restrict__ Wt,
    const float* __restrict__ bq, const float* __restrict__ bk, const float* __restrict__ bv,
    float* __restrict__ bcat,
    const float* __restrict__ rpe, float* __restrict__ posk, float* __restrict__ posq0)
{
  __shared__ float t[32][33];
  __shared__ float red[4][64];
  int b = blockIdx.x, tid = threadIdx.x;
  if (b < 4096){
    int w = b >> 10, tile = b & 1023;
    int k0 = (tile & 31) * 32, n0 = (tile >> 5) * 32;
    const float* W = (w == 0) ? Wq : (w == 1) ? Wk : (w == 2) ? Wv : Wo;
    u16* outp = Wt + (size_t)w * 1024 * 1024;
    int x = tid & 31, y = tid >> 5;
    #pragma unroll
    for (int yy = 0; yy < 32; yy += 8) t[y + yy][x] = W[(size_t)(k0 + y + yy) * 1024 + n0 + x];
    __syncthreads();
    #pragma unroll
    for (int yy = 0; yy < 32; yy += 8) outp[(size_t)(n0 + y + yy) * 1024 + k0 + x] = f2bf(t[x][y + yy]);
  } else if (b < 4608){
    int base = (b - 4096) * 8192;
    #pragma unroll
    for (int j = 0; j < 8; j++){
      int i = base + j * 1024 + tid * 4;
      float4 f = *(const float4*)&hidden[i];
      unsigned u0 = (unsigned)f2bf(f.x) | ((unsigned)f2bf(f.y) << 16);
      unsigned u1 = (unsigned)f2bf(f.z) | ((unsigned)f2bf(f.w) << 16);
      uint2 p; p.x = u0; p.y = u1;
      *(uint2*)&hb[i] = p;
    }
  } else if (b == 4608){
    #pragma unroll
    for (int j = 0; j < 12; j++){
      int i = j * 256 + tid;
      const float* src = i < 1024 ? bq : (i < 2048 ? bk : bv);
      bcat[i] = src[i & 1023];
    }
  } else {
    int pb = b - 4609;   // [0,257)
    int d = tid & 63, part = tid >> 6;
    const float* W  = (pb < 256) ? Wk : Wq;
    const float* rv = (pb < 256) ? &rpe[(size_t)pb * 1024] : rpe;
    float s = 0.f;
    for (int k = part * 256; k < part * 256 + 256; k++) s += rv[k] * W[(size_t)k * 1024 + d];
    red[part][d] = s;
    __syncthreads();
    if (part == 0){
      s = red[0][d] + red[1][d] + red[2][d] + red[3][d];
      if (pb < 256) posk[pb * 64 + d] = s + bk[d];
      else          posq0[d] = s + bq[d];
    }
  }
}

// ---------------- QKV GEMM (m97 structure): qk[S][2048] = Q|K ; Vt[c][s] for V ----------------
__global__ __launch_bounds__(256) void k_gemm_qkv(const u16* __restrict__ A, const u16* __restrict__ Bt,
                                                  const float* __restrict__ bias,
                                                  u16* __restrict__ qk, u16* __restrict__ Vt)
{
  __shared__ alignas(16) u16 As[128 * 32];
  __shared__ alignas(16) u16 Bs[128 * 32];
  int tid = threadIdx.x, lane = tid & 63, wid = tid >> 6;
  int wr = wid >> 1, wc = wid & 1;
  int m0 = blockIdx.y * 128, n0 = blockIdx.x * 128;
  const int K = 1024;

  v4f acc[4][4];
  #pragma unroll
  for (int m = 0; m < 4; m++)
    #pragma unroll
    for (int n = 0; n < 4; n++) acc[m][n] = (v4f){0.f, 0.f, 0.f, 0.f};

  int r = lane & 15, g = lane >> 4;
  int ob0 = wid * 2048;

  for (int kt = 0; kt < K; kt += 32){
    #pragma unroll
    for (int t = 0; t < 2; ++t){
      int ob = ob0 + t * 1024;
      int o  = ob + lane * 16;
      int row = o >> 6, col = (o & 63) >> 1;
      GLOAD_LDS16(&A [(size_t)(m0 + row) * K + kt + col], As + (ob >> 1));
      GLOAD_LDS16(&Bt[(size_t)(n0 + row) * K + kt + col], Bs + (ob >> 1));
    }
    __syncthreads();
    v8bf a[4], bb[4];
    #pragma unroll
    for (int m = 0; m < 4; m++) a[m] = *(const v8bf*)&As[(wr * 64 + m * 16 + r) * 32 + g * 8];
    #pragma unroll
    for (int n = 0; n < 4; n++) bb[n] = *(const v8bf*)&Bs[(wc * 64 + n * 16 + r) * 32 + g * 8];
    #pragma unroll
    for (int m = 0; m < 4; m++)
      #pragma unroll
      for (int n = 0; n < 4; n++)
        acc[m][n] = __builtin_amdgcn_mfma_f32_16x16x32_bf16(a[m], bb[n], acc[m][n], 0, 0, 0);
    __syncthreads();
  }

  #pragma unroll
  for (int m = 0; m < 4; m++)
    #pragma unroll
    for (int n = 0; n < 4; n++){
      int col = n0 + wc * 64 + n * 16 + r;
      float bv = bias[col];
      #pragma unroll
      for (int i = 0; i < 4; i++){
        int row = m0 + wr * 64 + m * 16 + g * 4 + i;
        u16 h = f2bf(acc[m][n][i] + bv);
        if (col < 2048) qk[(size_t)row * 2048 + col] = h;
        else            Vt[(size_t)(col - 2048) * 4096 + row] = h;   // V stored transposed
      }
    }
}

// ---------------- out GEMM + residual ----------------
__global__ __launch_bounds__(256) void k_gemm_out(const u16* __restrict__ A, const u16* __restrict__ Bt,
                                                  const float* __restrict__ bias,
                                                  const float* __restrict__ resid, float* __restrict__ Cout)
{
  __shared__ alignas(16) u16 As[128 * 32];
  __shared__ alignas(16) u16 Bs[128 * 32];
  int tid = threadIdx.x, lane = tid & 63, wid = tid >> 6;
  int wr = wid >> 1, wc = wid & 1;
  int m0 = blockIdx.y * 128, n0 = blockIdx.x * 128;
  const int K = 1024;

  v4f acc[4][4];
  #pragma unroll
  for (int m = 0; m < 4; m++)
    #pragma unroll
    for (int n = 0; n < 4; n++) acc[m][n] = (v4f){0.f, 0.f, 0.f, 0.f};

  int r = lane & 15, g = lane >> 4;
  int ob0 = wid * 2048;

  for (int kt = 0; kt < K; kt += 32){
    #pragma unroll
    for (int t = 0; t < 2; ++t){
      int ob = ob0 + t * 1024;
      int o  = ob + lane * 16;
      int row = o >> 6, col = (o & 63) >> 1;
      GLOAD_LDS16(&A [(size_t)(m0 + row) * K + kt + col], As + (ob >> 1));
      GLOAD_LDS16(&Bt[(size_t)(n0 + row) * K + kt + col], Bs + (ob >> 1));
    }
    __syncthreads();
    v8bf a[4], bb[4];
    #pragma unroll
    for (int m = 0; m < 4; m++) a[m] = *(const v8bf*)&As[(wr * 64 + m * 16 + r) * 32 + g * 8];
    #pragma unroll
    for (int n = 0; n < 4; n++) bb[n] = *(const v8bf*)&Bs[(wc * 64 + n * 16 + r) * 32 + g * 8];
    #pragma unroll
    for (int m = 0; m < 4; m++)
      #pragma unroll
      for (int n = 0; n < 4; n++)
        acc[m][n] = __builtin_amdgcn_mfma_f32_16x16x32_bf16(a[m], bb[n], acc[m][n], 0, 0, 0);
    __syncthreads();
  }

  #pragma unroll
  for (int m = 0; m < 4; m++)
    #pragma unroll
    for (int n = 0; n < 4; n++){
      int col = n0 + wc * 64 + n * 16 + r;
      float bv = bias[col];
      #pragma unroll
      for (int i = 0; i < 4; i++){
        int row = m0 + wr * 64 + m * 16 + g * 4 + i;
        Cout[(size_t)row * 1024 + col] = acc[m][n][i] + bv + resid[(size_t)row * 1024 + col];
      }
    }
}

// ---------------- brow: 8 WGs, 32 rows each; also zeros brow[0,256) ----------------
__global__ __launch_bounds__(256) void k_brow(const u16* __restrict__ qk,
                                              const float* __restrict__ posk, const float* __restrict__ posq0,
                                              float* __restrict__ brow)
{
  int b = blockIdx.x, tid = threadIdx.x;
  if (tid < 32) brow[b * 32 + tid] = 0.f;        // zero [0,256) across the 8 blocks
  int u = b * 32 + (tid >> 3), sub = tid & 7;
  float c2p = 0.f, p2c = 0.f;
  #pragma unroll
  for (int j = 0; j < 8; j++){
    int d = sub * 8 + j;
    c2p += bf2f(qk[d]) * posk[u * 64 + d];                   // q row0 head0
    p2c += posq0[d] * bf2f(qk[(size_t)u * 2048 + 1024 + d]); // k row u head0
  }
  float v = c2p + p2c;
  v += __shfl_xor(v, 1);
  v += __shfl_xor(v, 2);
  v += __shfl_xor(v, 4);
  if (sub == 0) brow[256 + u] = v;
}

// ---------------- biasd[t] = brow[clip(bucket(t-767)+256)] ----------------
__global__ void k_biasd(const float* __restrict__ brow, float* __restrict__ biasd)
{
  int t = blockIdx.x * blockDim.x + threadIdx.x;   // 1024
  int rel = t - 767;
  int bucket;
  bool in_exact = (rel < 128) && (rel > -128);
  int abs_pos = in_exact ? 127 : (rel < 0 ? -rel : rel);
  if (abs_pos <= 128) bucket = rel;
  else {
    float xx = logf((float)abs_pos * (1.0f / 128.0f)) / logf(255.0f / 128.0f);
    float lp = ceilf(xx * 127.0f) + 128.0f;
    int sgn = (rel > 0) ? 1 : ((rel < 0) ? -1 : 0);
    bucket = (int)lp * sgn;
  }
  int idx = bucket + 256;
  idx = idx < 0 ? 0 : (idx > 511 ? 511 : idx);
  biasd[t] = brow[idx];
}

// ---------------- flash-style local attention: WG = (64-row qtile, head) ----------------
// Online softmax; wave-private 16 rows (Q frags + m/l in regs, no cross-wave reduce).
// K [128][64] + V [64][128] staged per chunk via global_load_lds with pre-swizzled src.
__global__ __launch_bounds__(256) void k_attn(const u16* __restrict__ qk, const u16* __restrict__ Vt,
                                              const float* __restrict__ biasd, u16* __restrict__ ctxg)
{
  __shared__ alignas(16) u16 Ks[128 * 64];     // 16KB, slot-swizzled rows
  __shared__ alignas(16) u16 Vs[64 * 128];     // 16KB, slot-swizzled rows (d-major)
  __shared__ alignas(16) u16 Ps[4 * 16 * 128]; // 16KB, per-wave 16x128 probs
  __shared__ float bias_s[1024];

  int b = blockIdx.x;
  int h = b & 15, tile = b >> 4;               // 64 qtiles of 64 rows
  int n = tile >> 2, qb0 = (tile & 3) * 64;    // block + row-offset within block
  int tid = threadIdx.x, lane = tid & 63, w = tid >> 6;
  int q0 = tile * 64;
  int g0 = (n - 1) * 256;
  const float c1 = 0.07216878364870323f * 1.4426950408889634f;  // 1/sqrt(192)*log2e
  int r = lane & 15, g = lane >> 4;

  *(float4*)&bias_s[tid * 4] = *(const float4*)&biasd[tid * 4];

  // Q fragments in registers: wave w owns rows q0 + w*16 + [0,16)
  v8bf qfrag[2];
  {
    const u16* src = &qk[(size_t)(q0 + w * 16 + r) * 2048 + h * 64 + g * 8];
    qfrag[0] = *(const v8bf*)&src[0];
    qfrag[1] = *(const v8bf*)&src[32];
  }

  u16* Pw = &Ps[w * 2048];
  float m4[4], l4[4];
  v4f pacc[4];
  #pragma unroll
  for (int i = 0; i < 4; i++){ m4[i] = -3.0e38f; l4[i] = 0.f; pacc[i] = (v4f){0.f,0.f,0.f,0.f}; }

  for (int c = 0; c < 6; ++c){
    int cb = g0 + c * 128;
    bool oob = (cb < 0) || (cb >= SEQ);
    if (!oob){
      #pragma unroll
      for (int t = 0; t < 4; ++t){       // K rows w*32 + t*8 + (lane>>3)
        int row = w * 32 + t * 8 + (lane >> 3);
        int p = lane & 7;
        GLOAD_LDS16(&qk[(size_t)(cb + row) * 2048 + 1024 + h * 64 + ((p ^ (row & 7)) * 8)],
                    Ks + (size_t)(w * 32 + t * 8) * 64);
      }
      #pragma unroll
      for (int t = 0; t < 4; ++t){       // V d-rows w*16 + t*4 + (lane>>4)
        int d = w * 16 + t * 4 + (lane >> 4);
        int p = lane & 15;
        GLOAD_LDS16(&Vt[(size_t)(h * 64 + d) * 4096 + cb + ((p ^ (d & 7)) * 8)],
                    Vs + (size_t)(w * 16 + t * 4) * 128);
      }
    }
    __syncthreads();

    // QK: 8 key-tiles x 2 ks
    v4f sacc[8];
    #pragma unroll
    for (int t = 0; t < 8; t++) sacc[t] = (v4f){0.f,0.f,0.f,0.f};
    if (!oob){
      #pragma unroll
      for (int ks = 0; ks < 2; ++ks){
        #pragma unroll
        for (int t = 0; t < 8; t++){
          int kr = t * 16 + r;
          v8bf bb = *(const v8bf*)&Ks[kr * 64 + (((4 * ks + g) ^ (kr & 7)) * 8)];
          sacc[t] = __builtin_amdgcn_mfma_f32_16x16x32_bf16(qfrag[ks], bb, sacc[t], 0, 0, 0);
        }
      }
    }

    // scores + chunk max (bias idx = qb0 + qrow - kcol + 767)
    float sv[8][4];
    float cm[4] = {-3.0e38f, -3.0e38f, -3.0e38f, -3.0e38f};
    int ib = qb0 + g * 4 + 767 - r - c * 128;
    #pragma unroll
    for (int t = 0; t < 8; t++){
      #pragma unroll
      for (int i = 0; i < 4; i++){
        float s = (sacc[t][i] + bias_s[ib + i - t * 16]) * c1;
        sv[t][i] = s;
        cm[i] = fmaxf(cm[i], s);
      }
    }
    #pragma unroll
    for (int i = 0; i < 4; i++){
      cm[i] = fmaxf(cm[i], __shfl_xor(cm[i], 1));
      cm[i] = fmaxf(cm[i], __shfl_xor(cm[i], 2));
      cm[i] = fmaxf(cm[i], __shfl_xor(cm[i], 4));
      cm[i] = fmaxf(cm[i], __shfl_xor(cm[i], 8));
    }
    // online rescale
    #pragma unroll
    for (int i = 0; i < 4; i++){
      float mn = fmaxf(m4[i], cm[i]);
      float sc = exp2f(m4[i] - mn);
      m4[i] = mn;
      l4[i] *= sc;
      #pragma unroll
      for (int nn = 0; nn < 4; nn++) pacc[nn][i] *= sc;
    }
    // P = exp2(s - m), accumulate l, store bf16 (skip store for OOB)
    #pragma unroll
    for (int t = 0; t < 8; t++){
      #pragma unroll
      for (int i = 0; i < 4; i++){
        float p = exp2f(sv[t][i] - m4[i]);
        l4[i] += p;
        if (!oob){
          int row = g * 4 + i;
          Pw[row * 128 + (((2 * t + (r >> 3)) ^ (row & 7)) * 8) + (r & 7)] = f2bf(p);
        }
      }
    }

    // PV
    if (!oob){
      #pragma unroll
      for (int ks = 0; ks < 4; ++ks){
        v8bf a = *(const v8bf*)&Pw[r * 128 + (((4 * ks + g) ^ (r & 7)) * 8)];
        #pragma unroll
        for (int nn = 0; nn < 4; nn++){
          int d = nn * 16 + r;
          v8bf bb = *(const v8bf*)&Vs[d * 128 + (((4 * ks + g) ^ (d & 7)) * 8)];
          pacc[nn] = __builtin_amdgcn_mfma_f32_16x16x32_bf16(a, bb, pacc[nn], 0, 0, 0);
        }
      }
    }
    __syncthreads();   // protect Ks/Vs for next chunk
  }

  // final: reduce l over r lanes, normalize, store
  float inv4[4];
  #pragma unroll
  for (int i = 0; i < 4; i++){
    l4[i] += __shfl_xor(l4[i], 1);
    l4[i] += __shfl_xor(l4[i], 2);
    l4[i] += __shfl_xor(l4[i], 4);
    l4[i] += __shfl_xor(l4[i], 8);
    inv4[i] = 1.0f / l4[i];
  }
  #pragma unroll
  for (int nn = 0; nn < 4; nn++){
    int d = nn * 16 + r;
    #pragma unroll
    for (int i = 0; i < 4; i++){
      int qrow = q0 + w * 16 + g * 4 + i;
      ctxg[(size_t)qrow * 1024 + h * 64 + d] = f2bf(pacc[nn][i] * inv4[i]);
    }
  }
}

// ---------------- LayerNorm in place (residual already folded into out) ----------------
__global__ __launch_bounds__(256) void k_ln(float* __restrict__ out,
                                            const float* __restrict__ gamma, const float* __restrict__ beta)
{
  __shared__ float red[8];
  int row = blockIdx.x, tid = threadIdx.x;
  int lane = tid & 63, wid = tid >> 6;
  size_t base = (size_t)row * 1024 + tid * 4;
  float4 xv = *(const float4*)&out[base];
  float v0 = xv.x, v1 = xv.y, v2 = xv.z, v3 = xv.w;
  float s = v0 + v1 + v2 + v3;
  float q = v0 * v0 + v1 * v1 + v2 * v2 + v3 * v3;
  #pragma unroll
  for (int o = 32; o; o >>= 1){ s += __shfl_down(s, o); q += __shfl_down(q, o); }
  if (lane == 0){ red[wid] = s; red[4 + wid] = q; }
  __syncthreads();
  float ts = red[0] + red[1] + red[2] + red[3];
  float tq = red[4] + red[5] + red[6] + red[7];
  float mu = ts * (1.0f / 1024.0f);
  float var = tq * (1.0f / 1024.0f) - mu * mu;
  float rstd = rsqrtf(var + 1e-7f);
  int c = tid * 4;
  out[base + 0] = (v0 - mu) * rstd * gamma[c + 0] + beta[c + 0];
  out[base + 1] = (v1 - mu) * rstd * gamma[c + 1] + beta[c + 1];
  out[base + 2] = (v2 - mu) * rstd * gamma[c + 2] + beta[c + 2];
  out[base + 3] = (v3 - mu) * rstd * gamma[c + 3] + beta[c + 3];
}

extern "C" void kernel_launch(void* const* d_in, const int* in_sizes, int n_in,
                              void* d_out, int out_size, void* d_ws, size_t ws_size,
                              hipStream_t stream)
{
  const float* hidden = (const float*)d_in[0];
  const float* rpe    = (const float*)d_in[1];
  const float* Wq = (const float*)d_in[2];
  const float* bq = (const float*)d_in[3];
  const float* Wk = (const float*)d_in[4];
  const float* bk = (const float*)d_in[5];
  const float* Wv = (const float*)d_in[6];
  const float* bv = (const float*)d_in[7];
  const float* Wo = (const float*)d_in[8];
  const float* bo = (const float*)d_in[9];
  const float* lns = (const float*)d_in[10];
  const float* lnb = (const float*)d_in[11];
  float* out = (float*)d_out;

  char* ws = (char*)d_ws;
  size_t off = 0;
  auto alloc = [&](size_t bytes){ void* p = ws + off; off += (bytes + 255) & ~(size_t)255; return p; };
  u16* hb      = (u16*)alloc((size_t)SEQ * HIDN * 2);
  u16* Wt      = (u16*)alloc((size_t)4 * HIDN * HIDN * 2);    // [Wqt|Wkt|Wvt|Wot]
  u16* qk      = (u16*)alloc((size_t)SEQ * 2048 * 2);
  u16* Vt      = (u16*)alloc((size_t)HIDN * SEQ * 2);
  u16* ctxb    = (u16*)alloc((size_t)SEQ * HIDN * 2);
  float* bcat  = (float*)alloc(3072 * 4);
  float* poskf = (float*)alloc(256 * 64 * 4);
  float* posq0 = (float*)alloc(64 * 4);
  float* brow  = (float*)alloc(512 * 4);
  float* biasd = (float*)alloc(1024 * 4);
  (void)ws_size; (void)in_sizes; (void)n_in; (void)out_size;

  k_prep<<<4866, 256, 0, stream>>>(hidden, hb, Wq, Wk, Wv, Wo, Wt,
                                   bq, bk, bv, bcat, rpe, poskf, posq0);

  k_gemm_qkv<<<dim3(24, 32), 256, 0, stream>>>(hb, Wt, bcat, qk, Vt);

  k_brow<<<8, 256, 0, stream>>>(qk, poskf, posq0, brow);
  k_biasd<<<4, 256, 0, stream>>>(brow, biasd);

  k_attn<<<64 * NHEAD, 256, 0, stream>>>(qk, Vt, biasd, ctxb);

  k_gemm_out<<<dim3(8, 32), 256, 0, stream>>>(ctxb, Wt + (size_t)3 * HIDN * HIDN, bo, hidden, out);

  k_ln<<<SEQ, 256, 0, stream>>>(out, lns, lnb);
}